// Round 22
// baseline (130.597 us; speedup 1.0000x reference)
//
#include <hip/hip_runtime.h>
#include <hip/hip_bf16.h>
#include <stdint.h>

typedef unsigned short u16;
typedef unsigned int u32;
typedef __attribute__((ext_vector_type(4))) float f32x4;
typedef __attribute__((ext_vector_type(16))) float f32x16;
typedef __attribute__((ext_vector_type(8))) short bf16x8;
typedef __attribute__((ext_vector_type(4))) unsigned int u32x4;
typedef __attribute__((ext_vector_type(2))) unsigned int u32x2;

#define DEV __device__ __forceinline__

DEV u16 f2bf(float f) {
  union { float f; uint32_t u; } v; v.f = f;
  uint32_t u = v.u;
  return (u16)((u + 0x7fffu + ((u >> 16) & 1u)) >> 16);
}
DEV float bf2f(u16 h) {
  union { uint32_t u; float f; } v; v.u = ((uint32_t)h) << 16;
  return v.f;
}

DEV u32 cvtpk(float a, float b) {  // D.lo = bf16(a), D.hi = bf16(b), RNE
  u32 r;
  asm("v_cvt_pk_bf16_f32 %0, %1, %2" : "=v"(r) : "v"(a), "v"(b));
  return r;
}

// v_permlane32_swap_b32 a, b: a' = [a.lo32lanes, b.lo32lanes], b' = [a.hi, b.hi]
DEV void plswap(u32& a, u32& b) {
  asm("v_permlane32_swap_b32 %0, %1" : "+v"(a), "+v"(b));
}

// raw 2^x — single quarter-rate trans op
DEV float fexp2(float x) {
  float r;
  asm("v_exp_f32 %0, %1" : "=v"(r) : "v"(x));
  return r;
}

DEV void gload_lds16(const u16* g, u16* l) {
  __builtin_amdgcn_global_load_lds(
      (const __attribute__((address_space(1))) void*)g,
      (__attribute__((address_space(3))) void*)l, 16, 0, 0);
}

// ------- merged prep (blocks 0..4095) + tiled weight transpose (blocks 4096..5119) -------
__global__ __launch_bounds__(256) void prep_tw_kernel(
    const float* __restrict__ Q, const float* __restrict__ K, const float* __restrict__ V,
    const float* __restrict__ WQ, const float* __restrict__ WK, const float* __restrict__ WV,
    const float* __restrict__ WO,
    u16* __restrict__ Qb, u16* __restrict__ Kb, u16* __restrict__ Vb,
    u16* __restrict__ Wt, u16* __restrict__ Wot) {
  __shared__ __align__(16) u16 tl[64][72];
  const int tid = threadIdx.x;
  if (blockIdx.x < 4096) {
    const int i = blockIdx.x * 256 + tid;
#pragma unroll
    for (int it = 0; it < 3; ++it) {
      int idx = it * 1048576 + i;
      int which = idx >> 20, j = idx & 1048575;
      const float* src = which == 0 ? Q : (which == 1 ? K : V);
      u16* dst = which == 0 ? Qb : (which == 1 ? Kb : Vb);
      float4 v = ((const float4*)src)[j];
      u32x2 pk;
      pk[0] = (u32)f2bf(v.x) | ((u32)f2bf(v.y) << 16);
      pk[1] = (u32)f2bf(v.z) | ((u32)f2bf(v.w) << 16);
      *(u32x2*)(dst + (size_t)j * 4) = pk;
    }
    return;
  }
  const int bid = blockIdx.x - 4096;
  const float* src;
  u16* dst;
  int rstride;
  if (bid < 768) {
    int p = bid >> 8, rest = bid & 255;
    int h = rest >> 4, dt = rest & 15;
    const float* W = p == 0 ? WQ : (p == 1 ? WK : WV);
    src = W + (size_t)(h * 1024 + dt * 64) * 64;       // rows = d (stride 64 floats)
    dst = Wt + (size_t)p * 1048576 + (size_t)h * 64 * 1024 + dt * 64;  // rows = k
    rstride = 64;
  } else {
    int idx2 = bid - 768;
    int kt = idx2 >> 4, ct = idx2 & 15;
    src = WO + (size_t)kt * 64 * 1024 + ct * 64;       // rows = k (stride 1024 floats)
    dst = Wot + (size_t)ct * 64 * 1024 + kt * 64;      // rows = c
    rstride = 1024;
  }
#pragma unroll
  for (int i = 0; i < 2; ++i) {
    int idx = i * 256 + tid;
    int row = idx >> 3, c8 = idx & 7;
    const float* sp = src + (size_t)row * rstride + c8 * 8;
    float4 a = *(const float4*)sp;
    float4 b = *(const float4*)(sp + 4);
    u32x4 pk;
    pk[0] = (u32)f2bf(a.x) | ((u32)f2bf(a.y) << 16);
    pk[1] = (u32)f2bf(a.z) | ((u32)f2bf(a.w) << 16);
    pk[2] = (u32)f2bf(b.x) | ((u32)f2bf(b.y) << 16);
    pk[3] = (u32)f2bf(b.z) | ((u32)f2bf(b.w) << 16);
    *(u32x4*)&tl[row][c8 * 8] = pk;
  }
  __syncthreads();
#pragma unroll
  for (int i = 0; i < 2; ++i) {
    int idx = i * 256 + tid;
    int row2 = idx >> 3, s8 = idx & 7;
    u32x4 outv;
    u16* tp = (u16*)&outv;
#pragma unroll
    for (int j = 0; j < 8; ++j) tp[j] = tl[s8 * 8 + j][row2];
    *(u32x4*)(dst + (size_t)row2 * 1024 + s8 * 8) = outv;
  }
}

// ---------------- proj GEMM: C[4096][1024] = A * Bt^T, z-batched (r17/r19-verified) ----------------
// z==2 (V projection) writes its output TRANSPOSED into VtOut[(b*16+h)*64+dk][s].
__global__ __launch_bounds__(256, 3) void gemm_proj_kernel(const u16* __restrict__ A,
                                                           const u16* __restrict__ Bt,
                                                           u16* __restrict__ Cout,
                                                           u16* __restrict__ VtOut) {
  __shared__ __align__(16) u16 Alds[128 * 64];
  __shared__ __align__(16) u16 Blds[128 * 64];
  const size_t zo = blockIdx.z;
  A += zo * 4194304;
  Bt += zo * 1048576;
  const int tid = threadIdx.x;
  const int l = tid & 63, w = tid >> 6;
  const int wm = w >> 1, wn = w & 1;
  const int d = blockIdx.x + 32 * blockIdx.y;
  const int orig = (d & 7) * 32 + (d >> 3);
  const int tileM = (orig & 31) * 128, tileN = (orig >> 5) * 128;
  const int lr = l >> 3, lch = l & 7;

  f32x4 acc[4][4] = {};

  for (int kt = 0; kt < 16; ++kt) {
    const int k0 = kt * 64;
#pragma unroll
    for (int i = 0; i < 4; ++i) {
      int r = i * 32 + w * 8 + lr;
      int sch = lch ^ (r & 7);
      gload_lds16(A + (size_t)(tileM + r) * 1024 + k0 + sch * 8, Alds + i * 2048 + w * 512);
      gload_lds16(Bt + (size_t)(tileN + r) * 1024 + k0 + sch * 8, Blds + i * 2048 + w * 512);
    }
    __syncthreads();
    bf16x8 af[4][2], bfr[4][2];
#pragma unroll
    for (int m = 0; m < 4; ++m) {
#pragma unroll
      for (int kk = 0; kk < 2; ++kk) {
        int row = wm * 64 + m * 16 + (l & 15);
        int ch = ((l >> 4) + kk * 4) ^ (row & 7);
        af[m][kk] = *(const bf16x8*)(Alds + row * 64 + ch * 8);
        int rowb = wn * 64 + m * 16 + (l & 15);
        int chb = ((l >> 4) + kk * 4) ^ (rowb & 7);
        bfr[m][kk] = *(const bf16x8*)(Blds + rowb * 64 + chb * 8);
      }
    }
#pragma unroll
    for (int m = 0; m < 4; ++m)
#pragma unroll
      for (int n = 0; n < 4; ++n)
#pragma unroll
        for (int kk = 0; kk < 2; ++kk)
          acc[m][n] = __builtin_amdgcn_mfma_f32_16x16x32_bf16(af[m][kk], bfr[n][kk], acc[m][n], 0, 0, 0);
    __syncthreads();
  }
#pragma unroll
  for (int m = 0; m < 4; ++m) {
    int row0 = tileM + wm * 64 + m * 16 + ((l >> 4) << 2);
#pragma unroll
    for (int n = 0; n < 4; ++n) {
      int col = tileN + wn * 64 + n * 16 + (l & 15);
#pragma unroll
      for (int q = 0; q < 4; ++q) {
        u16 val = f2bf(acc[m][n][q]);
        if (zo == 2) {
          int g = row0 + q;                 // = b*2048 + s
          int bq = g >> 11, s = g & 2047;
          int hh = col >> 6, dk = col & 63;
          VtOut[((((size_t)bq << 4) + hh) * 64 + dk) * 2048 + s] = val;
        } else {
          Cout[zo * 4194304 + (size_t)(row0 + q) * 1024 + col] = val;
        }
      }
    }
  }
}

// ---------------- out GEMM with FUSED combine: A = (Op0+Op1)/(L0+L1) staged on the fly ----------
// 64x128 tiles, 512 blocks = 2 blocks/CU (r19-verified geometry). A-staging pattern
// (reg-load -> cvtpk -> linear ds_write to gload_lds-compatible dest) correctness-verified r18.
// fac row index: flat offset row*1024+col -> L-row gl = row*16 + kt (col>>6 == kt per chunk).
__global__ __launch_bounds__(256, 4) void gemm_out_kernel(const u16* __restrict__ Op0,
                                                          const u16* __restrict__ Op1,
                                                          const float* __restrict__ Lp,
                                                          const u16* __restrict__ Bt,
                                                          float* __restrict__ Cout) {
  __shared__ __align__(16) u16 Alds[64 * 64];    // 8 KB
  __shared__ __align__(16) u16 Blds[128 * 64];   // 16 KB
  const int tid = threadIdx.x;
  const int l = tid & 63, w = tid >> 6;
  const int wm = w >> 1, wn = w & 1;  // waves 2M x 2N: wave = 32 rows x 64 cols
  const int d = blockIdx.x;
  const int orig = (d & 7) * 64 + (d >> 3);          // bijective (512 % 8 == 0)
  const int tileM = (orig >> 3) * 64, tileN = (orig & 7) * 128;
  const int lr = l >> 3, lch = l & 7;

  f32x4 acc[2][4] = {};

  for (int kt = 0; kt < 16; ++kt) {
    const int k0 = kt * 64;
    // B staged async (keeps the pipeline); A combined+staged in regs (verified pattern)
#pragma unroll
    for (int i = 0; i < 4; ++i) {
      int r = i * 32 + w * 8 + lr;
      int sch = lch ^ (r & 7);
      gload_lds16(Bt + (size_t)(tileN + r) * 1024 + k0 + sch * 8, Blds + i * 2048 + w * 512);
    }
#pragma unroll
    for (int i = 0; i < 2; ++i) {
      int r = i * 32 + w * 8 + lr;
      int row = tileM + r;
      int sch = lch ^ (r & 7);
      const size_t foff = (size_t)row * 1024 + k0 + sch * 8;
      u32x4 va = *(const u32x4*)(Op0 + foff);
      u32x4 vb = *(const u32x4*)(Op1 + foff);
      int gl = row * 16 + kt;
      float fac = 1.f / (Lp[gl] + Lp[65536 + gl]);
      const u16* pa = (const u16*)&va;
      const u16* pb = (const u16*)&vb;
      u32x4 pk;
#pragma unroll
      for (int e = 0; e < 4; ++e)
        pk[e] = cvtpk((bf2f(pa[2 * e]) + bf2f(pb[2 * e])) * fac,
                      (bf2f(pa[2 * e + 1]) + bf2f(pb[2 * e + 1])) * fac);
      *(u32x4*)(Alds + i * 2048 + w * 512 + l * 8) = pk;
    }
    __syncthreads();
    bf16x8 af[2][2], bfr[4][2];
#pragma unroll
    for (int m = 0; m < 2; ++m)
#pragma unroll
      for (int kk = 0; kk < 2; ++kk) {
        int row = wm * 32 + m * 16 + (l & 15);
        int ch = ((l >> 4) + kk * 4) ^ (row & 7);
        af[m][kk] = *(const bf16x8*)(Alds + row * 64 + ch * 8);
      }
#pragma unroll
    for (int n = 0; n < 4; ++n)
#pragma unroll
      for (int kk = 0; kk < 2; ++kk) {
        int rowb = wn * 64 + n * 16 + (l & 15);
        int chb = ((l >> 4) + kk * 4) ^ (rowb & 7);
        bfr[n][kk] = *(const bf16x8*)(Blds + rowb * 64 + chb * 8);
      }
#pragma unroll
    for (int m = 0; m < 2; ++m)
#pragma unroll
      for (int n = 0; n < 4; ++n)
#pragma unroll
        for (int kk = 0; kk < 2; ++kk)
          acc[m][n] = __builtin_amdgcn_mfma_f32_16x16x32_bf16(af[m][kk], bfr[n][kk], acc[m][n], 0, 0, 0);
    __syncthreads();
  }
#pragma unroll
  for (int m = 0; m < 2; ++m) {
    int row0 = tileM + wm * 32 + m * 16 + ((l >> 4) << 2);
#pragma unroll
    for (int n = 0; n < 4; ++n) {
      int col = tileN + wn * 64 + n * 16 + (l & 15);
#pragma unroll
      for (int q = 0; q < 4; ++q)
        Cout[(size_t)(row0 + q) * 1024 + col] = acc[m][n][q];
    }
  }
}

// ---------------- flash attention: LDS-staged K/V + in-register softmax ----------------
// r13/r15/r17/r19-verified config: kv-split 2, fexp2 + plswap + VALU row-sum, LB(256,4).
__global__ __launch_bounds__(256, 4) void attn_kernel(const u16* __restrict__ Qi,
                                                      const u16* __restrict__ Ki,
                                                      const u16* __restrict__ Vt,
                                                      u16* __restrict__ Op,
                                                      float* __restrict__ Lp) {
  __shared__ __align__(16) u16 Kl[2][4096];
  __shared__ __align__(16) u16 Vl[2][4096];
  const int tid = threadIdx.x;
  const int l = tid & 63, w = tid >> 6;
  const int lq = l & 31, hi = l >> 5;
  const int lr = l >> 3, lch = l & 7;
  // bijective XCD chunk swizzle: 1024 blocks, XCD dd%8 gets 128 contiguous (=4 bh)
  const int dd = blockIdx.x;
  const int orig = (dd & 7) * 128 + (dd >> 3);
  const int bh = orig >> 5;
  const int rem = orig & 31;
  const int qb = rem >> 1, kvh = rem & 1;
  const int b = bh >> 4, h = bh & 15;
  const int qt = qb * 128 + w * 32;
  const int tb = kvh * 1024;

  const u16* Kbase = Ki + (size_t)b * 2048 * 1024 + h * 64;
  const u16* Vbase = Vt + (size_t)bh * 64 * 2048;

  // Q B-frags (col q = lq, k = s*16 + hi*8 + j), prescaled by log2(e)/8 (exp2 domain)
  bf16x8 qf[4];
  {
    const u16* qp = Qi + (size_t)(b * 2048 + qt + lq) * 1024 + h * 64 + hi * 8;
#pragma unroll
    for (int s = 0; s < 4; ++s) {
      u32x4 t4 = *(const u32x4*)(qp + s * 16);
      u16* tp = (u16*)&t4;
#pragma unroll
      for (int j = 0; j < 8; ++j) tp[j] = f2bf(bf2f(tp[j]) * 0.1803368867f);
      qf[s] = *(bf16x8*)&t4;
    }
  }

  f32x16 o0 = {}, o1 = {};
  float l_r = 0.f;

  // stage tile `t` into buffer `bb`: K [64 t-rows][64 k], V^T [64 d-rows][64 t]
  auto STAGE = [&](int bb, int t) {
#pragma unroll
    for (int i = 0; i < 2; ++i) {
      int r = i * 32 + w * 8 + lr;
      int sch = lch ^ (r & 7);
      gload_lds16(Kbase + (size_t)(tb + t * 64 + r) * 1024 + sch * 8,
                  Kl[bb] + i * 2048 + w * 512);
      gload_lds16(Vbase + (size_t)r * 2048 + tb + t * 64 + sch * 8,
                  Vl[bb] + i * 2048 + w * 512);
    }
  };

  STAGE(0, 0);

#pragma unroll 2
  for (int tile = 0; tile < 16; ++tile) {
    const int cur = tile & 1;
    __syncthreads();  // compiler drains vmcnt: staged tile `cur` ready
    if (tile + 1 < 16) STAGE(cur ^ 1, tile + 1);
    const u16* kl = Kl[cur];
    const u16* vl = Vl[cur];

    // S^T = K Q^T: two 32-t halves
    f32x16 s0 = {}, s1 = {};
    __builtin_amdgcn_s_setprio(1);
#pragma unroll
    for (int s = 0; s < 4; ++s) {
      int row = lq, c = s * 2 + hi;
      bf16x8 kf = *(const bf16x8*)(kl + row * 64 + (c ^ (row & 7)) * 8);
      s0 = __builtin_amdgcn_mfma_f32_32x32x16_bf16(kf, qf[s], s0, 0, 0, 0);
    }
#pragma unroll
    for (int s = 0; s < 4; ++s) {
      int row = 32 + lq, c = s * 2 + hi;
      bf16x8 kf = *(const bf16x8*)(kl + row * 64 + (c ^ (row & 7)) * 8);
      s1 = __builtin_amdgcn_mfma_f32_32x32x16_bf16(kf, qf[s], s1, 0, 0, 0);
    }
    __builtin_amdgcn_s_setprio(0);

    // P = exp2(S) via raw v_exp_f32; row-sum tree on VALU; pack; permlane half-swap
    float rs = 0.f;
    bf16x8 pa[4];
#pragma unroll
    for (int s4 = 0; s4 < 4; ++s4) {
      const int rb = 8 * (s4 & 1);
      float p[8];
#pragma unroll
      for (int j = 0; j < 8; ++j) {
        float sv = (s4 < 2) ? ((const float*)&s0)[rb + j] : ((const float*)&s1)[rb + j];
        p[j] = fexp2(sv);
      }
      rs += ((p[0] + p[1]) + (p[2] + p[3])) + ((p[4] + p[5]) + (p[6] + p[7]));
      u32 w10 = cvtpk(p[0], p[1]);
      u32 w11 = cvtpk(p[2], p[3]);
      u32 w20 = cvtpk(p[4], p[5]);
      u32 w21 = cvtpk(p[6], p[7]);
      plswap(w10, w20);  // w10 -> [w10.lo, w20.lo]; w20 -> [w10.hi, w20.hi]
      plswap(w11, w21);
      u32x4 af;
      af[0] = w10;
      af[1] = w11;
      af[2] = w20;
      af[3] = w21;
      pa[s4] = *(bf16x8*)&af;  // t-window s4*16
    }
    rs += __shfl_xor(rs, 32, 64);
    l_r += rs;

    // O += P V
    __builtin_amdgcn_s_setprio(1);
#pragma unroll
    for (int s4 = 0; s4 < 4; ++s4) {
      int rowd = lq, c = s4 * 2 + hi;
      bf16x8 vf = *(const bf16x8*)(vl + rowd * 64 + (c ^ (rowd & 7)) * 8);
      o0 = __builtin_amdgcn_mfma_f32_32x32x16_bf16(pa[s4], vf, o0, 0, 0, 0);
    }
#pragma unroll
    for (int s4 = 0; s4 < 4; ++s4) {
      int rowd = 32 + lq, c = s4 * 2 + hi;
      bf16x8 vf = *(const bf16x8*)(vl + rowd * 64 + (c ^ (rowd & 7)) * 8);
      o1 = __builtin_amdgcn_mfma_f32_32x32x16_bf16(pa[s4], vf, o1, 0, 0, 0);
    }
    __builtin_amdgcn_s_setprio(0);
  }

  // write unnormalized partials (D-layout: q(reg r) = (r&3)+8*(r>>2)+4*hi, d-col = lq)
#pragma unroll
  for (int r = 0; r < 16; ++r) {
    int qr = (r & 3) + 8 * (r >> 2) + 4 * hi;
    u16* hp = Op + (size_t)kvh * 4194304 + ((size_t)bh * 2048 + qt + qr) * 64;
    hp[lq] = f2bf(o0[r]);
    hp[32 + lq] = f2bf(o1[r]);
  }
  if (hi == 0) Lp[(size_t)kvh * 65536 + (size_t)bh * 2048 + qt + lq] = l_r;
}

// ---------------- launch ----------------
extern "C" void kernel_launch(void* const* d_in, const int* in_sizes, int n_in,
                              void* d_out, int out_size, void* d_ws, size_t ws_size,
                              hipStream_t stream) {
  const float* Q = (const float*)d_in[0];
  const float* K = (const float*)d_in[1];
  const float* V = (const float*)d_in[2];
  const float* WQ = (const float*)d_in[3];
  const float* WK = (const float*)d_in[4];
  const float* WV = (const float*)d_in[5];
  const float* WO = (const float*)d_in[6];
  float* out = (float*)d_out;

  size_t off = 0;
  char* ws = (char*)d_ws;
  auto nxt = [&](size_t n) { void* p = ws + off; off += (n + 255) & ~(size_t)255; return p; };
  u16* Qb = (u16*)nxt(3ull * 4096 * 1024 * 2);   // Qb,Kb,Vb contiguous (dead after proj GEMM)
  u16* Qi = (u16*)nxt(3ull * 4096 * 1024 * 2);   // Qi,Ki (z=2 writes Vtb instead)
  u16* Vtb = (u16*)nxt(4096ull * 1024 * 2);
  u16* Wt = (u16*)nxt(3ull * 1048576 * 2);
  u16* Wot = (u16*)nxt(1048576ull * 2);
  float* Lp = (float*)nxt(2ull * 65536 * 4);
  u16* Ki = Qi + 4194304;
  // attention partials: Op[0..1] alias dead Qb region (16.8MB < 25.2MB)
  u16* Op = Qb;

  prep_tw_kernel<<<5120, 256, 0, stream>>>(Q, K, V, WQ, WK, WV, WO, Qb, Qb + 4194304,
                                           Qb + 2 * 4194304, Wt, Wot);

  // fused Q/K/V projections: z picks (A, W, C) triple; z==2 writes Vtb transposed
  gemm_proj_kernel<<<dim3(32, 8, 3), 256, 0, stream>>>(Qb, Wt, Qi, Vtb);

  attn_kernel<<<1024, 256, 0, stream>>>(Qi, Ki, Vtb, Op, Lp);

  // out projection with fused combine: A = (Op0+Op1)/(L0+L1), staged in-kernel
  gemm_out_kernel<<<512, 256, 0, stream>>>(Op, Op + 4194304, Lp, Wot, out);
}

// Round 23
// 124.993 us; speedup vs baseline: 1.0448x; 1.0448x over previous
//
#include <hip/hip_runtime.h>
#include <hip/hip_bf16.h>
#include <stdint.h>

typedef unsigned short u16;
typedef unsigned int u32;
typedef __attribute__((ext_vector_type(4))) float f32x4;
typedef __attribute__((ext_vector_type(16))) float f32x16;
typedef __attribute__((ext_vector_type(8))) short bf16x8;
typedef __attribute__((ext_vector_type(4))) unsigned int u32x4;
typedef __attribute__((ext_vector_type(2))) unsigned int u32x2;

#define DEV __device__ __forceinline__

DEV u16 f2bf(float f) {
  union { float f; uint32_t u; } v; v.f = f;
  uint32_t u = v.u;
  return (u16)((u + 0x7fffu + ((u >> 16) & 1u)) >> 16);
}
DEV float bf2f(u16 h) {
  union { uint32_t u; float f; } v; v.u = ((uint32_t)h) << 16;
  return v.f;
}

DEV u32 cvtpk(float a, float b) {  // D.lo = bf16(a), D.hi = bf16(b), RNE
  u32 r;
  asm("v_cvt_pk_bf16_f32 %0, %1, %2" : "=v"(r) : "v"(a), "v"(b));
  return r;
}

// v_permlane32_swap_b32 a, b: a' = [a.lo32lanes, b.lo32lanes], b' = [a.hi, b.hi]
DEV void plswap(u32& a, u32& b) {
  asm("v_permlane32_swap_b32 %0, %1" : "+v"(a), "+v"(b));
}

// raw 2^x — single quarter-rate trans op
DEV float fexp2(float x) {
  float r;
  asm("v_exp_f32 %0, %1" : "=v"(r) : "v"(x));
  return r;
}

DEV void gload_lds16(const u16* g, u16* l) {
  __builtin_amdgcn_global_load_lds(
      (const __attribute__((address_space(1))) void*)g,
      (__attribute__((address_space(3))) void*)l, 16, 0, 0);
}

// ------- merged prep (blocks 0..4095) + tiled weight transpose (blocks 4096..5119) -------
__global__ __launch_bounds__(256) void prep_tw_kernel(
    const float* __restrict__ Q, const float* __restrict__ K, const float* __restrict__ V,
    const float* __restrict__ WQ, const float* __restrict__ WK, const float* __restrict__ WV,
    const float* __restrict__ WO,
    u16* __restrict__ Qb, u16* __restrict__ Kb, u16* __restrict__ Vb,
    u16* __restrict__ Wt, u16* __restrict__ Wot) {
  __shared__ __align__(16) u16 tl[64][72];
  const int tid = threadIdx.x;
  if (blockIdx.x < 4096) {
    const int i = blockIdx.x * 256 + tid;
#pragma unroll
    for (int it = 0; it < 3; ++it) {
      int idx = it * 1048576 + i;
      int which = idx >> 20, j = idx & 1048575;
      const float* src = which == 0 ? Q : (which == 1 ? K : V);
      u16* dst = which == 0 ? Qb : (which == 1 ? Kb : Vb);
      float4 v = ((const float4*)src)[j];
      u32x2 pk;
      pk[0] = (u32)f2bf(v.x) | ((u32)f2bf(v.y) << 16);
      pk[1] = (u32)f2bf(v.z) | ((u32)f2bf(v.w) << 16);
      *(u32x2*)(dst + (size_t)j * 4) = pk;
    }
    return;
  }
  const int bid = blockIdx.x - 4096;
  const float* src;
  u16* dst;
  int rstride;
  if (bid < 768) {
    int p = bid >> 8, rest = bid & 255;
    int h = rest >> 4, dt = rest & 15;
    const float* W = p == 0 ? WQ : (p == 1 ? WK : WV);
    src = W + (size_t)(h * 1024 + dt * 64) * 64;       // rows = d (stride 64 floats)
    dst = Wt + (size_t)p * 1048576 + (size_t)h * 64 * 1024 + dt * 64;  // rows = k
    rstride = 64;
  } else {
    int idx2 = bid - 768;
    int kt = idx2 >> 4, ct = idx2 & 15;
    src = WO + (size_t)kt * 64 * 1024 + ct * 64;       // rows = k (stride 1024 floats)
    dst = Wot + (size_t)ct * 64 * 1024 + kt * 64;      // rows = c
    rstride = 1024;
  }
#pragma unroll
  for (int i = 0; i < 2; ++i) {
    int idx = i * 256 + tid;
    int row = idx >> 3, c8 = idx & 7;
    const float* sp = src + (size_t)row * rstride + c8 * 8;
    float4 a = *(const float4*)sp;
    float4 b = *(const float4*)(sp + 4);
    u32x4 pk;
    pk[0] = (u32)f2bf(a.x) | ((u32)f2bf(a.y) << 16);
    pk[1] = (u32)f2bf(a.z) | ((u32)f2bf(a.w) << 16);
    pk[2] = (u32)f2bf(b.x) | ((u32)f2bf(b.y) << 16);
    pk[3] = (u32)f2bf(b.z) | ((u32)f2bf(b.w) << 16);
    *(u32x4*)&tl[row][c8 * 8] = pk;
  }
  __syncthreads();
#pragma unroll
  for (int i = 0; i < 2; ++i) {
    int idx = i * 256 + tid;
    int row2 = idx >> 3, s8 = idx & 7;
    u32x4 outv;
    u16* tp = (u16*)&outv;
#pragma unroll
    for (int j = 0; j < 8; ++j) tp[j] = tl[s8 * 8 + j][row2];
    *(u32x4*)(dst + (size_t)row2 * 1024 + s8 * 8) = outv;
  }
}

// ---------------- proj GEMM: C[4096][1024] = A * Bt^T, z-batched ----------------
// XCD swizzle FIX (r22 profile: N-panel variant streamed all of A per XCD -> FETCH 101MB):
// M-panel: XCD x owns tileM in [4x,4x+4) x all 8 N -> A panel 1MB (read once, L2-resident)
// + B 2MB/z resident per XCD. z==2 writes output transposed into VtOut.
__global__ __launch_bounds__(256, 3) void gemm_proj_kernel(const u16* __restrict__ A,
                                                           const u16* __restrict__ Bt,
                                                           u16* __restrict__ Cout,
                                                           u16* __restrict__ VtOut) {
  __shared__ __align__(16) u16 Alds[128 * 64];
  __shared__ __align__(16) u16 Blds[128 * 64];
  const size_t zo = blockIdx.z;
  A += zo * 4194304;
  Bt += zo * 1048576;
  const int tid = threadIdx.x;
  const int l = tid & 63, w = tid >> 6;
  const int wm = w >> 1, wn = w & 1;
  const int d = blockIdx.x + 32 * blockIdx.y;
  const int orig = (d & 7) * 32 + (d >> 3);
  const int tileM = (orig >> 3) * 128, tileN = (orig & 7) * 128;   // M-panel per XCD
  const int lr = l >> 3, lch = l & 7;

  f32x4 acc[4][4] = {};

  for (int kt = 0; kt < 16; ++kt) {
    const int k0 = kt * 64;
#pragma unroll
    for (int i = 0; i < 4; ++i) {
      int r = i * 32 + w * 8 + lr;
      int sch = lch ^ (r & 7);
      gload_lds16(A + (size_t)(tileM + r) * 1024 + k0 + sch * 8, Alds + i * 2048 + w * 512);
      gload_lds16(Bt + (size_t)(tileN + r) * 1024 + k0 + sch * 8, Blds + i * 2048 + w * 512);
    }
    __syncthreads();
    bf16x8 af[4][2], bfr[4][2];
#pragma unroll
    for (int m = 0; m < 4; ++m) {
#pragma unroll
      for (int kk = 0; kk < 2; ++kk) {
        int row = wm * 64 + m * 16 + (l & 15);
        int ch = ((l >> 4) + kk * 4) ^ (row & 7);
        af[m][kk] = *(const bf16x8*)(Alds + row * 64 + ch * 8);
        int rowb = wn * 64 + m * 16 + (l & 15);
        int chb = ((l >> 4) + kk * 4) ^ (rowb & 7);
        bfr[m][kk] = *(const bf16x8*)(Blds + rowb * 64 + chb * 8);
      }
    }
#pragma unroll
    for (int m = 0; m < 4; ++m)
#pragma unroll
      for (int n = 0; n < 4; ++n)
#pragma unroll
        for (int kk = 0; kk < 2; ++kk)
          acc[m][n] = __builtin_amdgcn_mfma_f32_16x16x32_bf16(af[m][kk], bfr[n][kk], acc[m][n], 0, 0, 0);
    __syncthreads();
  }
#pragma unroll
  for (int m = 0; m < 4; ++m) {
    int row0 = tileM + wm * 64 + m * 16 + ((l >> 4) << 2);
#pragma unroll
    for (int n = 0; n < 4; ++n) {
      int col = tileN + wn * 64 + n * 16 + (l & 15);
#pragma unroll
      for (int q = 0; q < 4; ++q) {
        u16 val = f2bf(acc[m][n][q]);
        if (zo == 2) {
          int g = row0 + q;                 // = b*2048 + s
          int bq = g >> 11, s = g & 2047;
          int hh = col >> 6, dk = col & 63;
          VtOut[((((size_t)bq << 4) + hh) * 64 + dk) * 2048 + s] = val;
        } else {
          Cout[zo * 4194304 + (size_t)(row0 + q) * 1024 + col] = val;
        }
      }
    }
  }
}

// ---------------- out GEMM: 64x128 tiles, 512 blocks = 2 blocks/CU (r19-verified) ----------------
__global__ __launch_bounds__(256, 4) void gemm_out_kernel(const u16* __restrict__ A,
                                                          const u16* __restrict__ Bt,
                                                          float* __restrict__ Cout) {
  __shared__ __align__(16) u16 Alds[64 * 64];    // 8 KB
  __shared__ __align__(16) u16 Blds[128 * 64];   // 16 KB
  const int tid = threadIdx.x;
  const int l = tid & 63, w = tid >> 6;
  const int wm = w >> 1, wn = w & 1;  // waves 2M x 2N: wave = 32 rows x 64 cols
  const int d = blockIdx.x;
  const int orig = (d & 7) * 64 + (d >> 3);          // bijective (512 % 8 == 0)
  const int tileM = (orig >> 3) * 64, tileN = (orig & 7) * 128;
  const int lr = l >> 3, lch = l & 7;

  f32x4 acc[2][4] = {};

  for (int kt = 0; kt < 16; ++kt) {
    const int k0 = kt * 64;
#pragma unroll
    for (int i = 0; i < 2; ++i) {
      int r = i * 32 + w * 8 + lr;
      int sch = lch ^ (r & 7);
      gload_lds16(A + (size_t)(tileM + r) * 1024 + k0 + sch * 8, Alds + i * 2048 + w * 512);
    }
#pragma unroll
    for (int i = 0; i < 4; ++i) {
      int r = i * 32 + w * 8 + lr;
      int sch = lch ^ (r & 7);
      gload_lds16(Bt + (size_t)(tileN + r) * 1024 + k0 + sch * 8, Blds + i * 2048 + w * 512);
    }
    __syncthreads();
    bf16x8 af[2][2], bfr[4][2];
#pragma unroll
    for (int m = 0; m < 2; ++m)
#pragma unroll
      for (int kk = 0; kk < 2; ++kk) {
        int row = wm * 32 + m * 16 + (l & 15);
        int ch = ((l >> 4) + kk * 4) ^ (row & 7);
        af[m][kk] = *(const bf16x8*)(Alds + row * 64 + ch * 8);
      }
#pragma unroll
    for (int n = 0; n < 4; ++n)
#pragma unroll
      for (int kk = 0; kk < 2; ++kk) {
        int rowb = wn * 64 + n * 16 + (l & 15);
        int chb = ((l >> 4) + kk * 4) ^ (rowb & 7);
        bfr[n][kk] = *(const bf16x8*)(Blds + rowb * 64 + chb * 8);
      }
#pragma unroll
    for (int m = 0; m < 2; ++m)
#pragma unroll
      for (int n = 0; n < 4; ++n)
#pragma unroll
        for (int kk = 0; kk < 2; ++kk)
          acc[m][n] = __builtin_amdgcn_mfma_f32_16x16x32_bf16(af[m][kk], bfr[n][kk], acc[m][n], 0, 0, 0);
    __syncthreads();
  }
#pragma unroll
  for (int m = 0; m < 2; ++m) {
    int row0 = tileM + wm * 32 + m * 16 + ((l >> 4) << 2);
#pragma unroll
    for (int n = 0; n < 4; ++n) {
      int col = tileN + wn * 64 + n * 16 + (l & 15);
#pragma unroll
      for (int q = 0; q < 4; ++q)
        Cout[(size_t)(row0 + q) * 1024 + col] = acc[m][n][q];
    }
  }
}

// ---------------- flash attention: LDS-staged K/V + in-register softmax ----------------
// r13/r15/r17/r19/r21-verified config: kv-split 2, fexp2 + plswap + VALU row-sum, LB(256,4).
__global__ __launch_bounds__(256, 4) void attn_kernel(const u16* __restrict__ Qi,
                                                      const u16* __restrict__ Ki,
                                                      const u16* __restrict__ Vt,
                                                      u16* __restrict__ Op,
                                                      float* __restrict__ Lp) {
  __shared__ __align__(16) u16 Kl[2][4096];
  __shared__ __align__(16) u16 Vl[2][4096];
  const int tid = threadIdx.x;
  const int l = tid & 63, w = tid >> 6;
  const int lq = l & 31, hi = l >> 5;
  const int lr = l >> 3, lch = l & 7;
  // bijective XCD chunk swizzle: 1024 blocks, XCD dd%8 gets 128 contiguous (=4 bh)
  const int dd = blockIdx.x;
  const int orig = (dd & 7) * 128 + (dd >> 3);
  const int bh = orig >> 5;
  const int rem = orig & 31;
  const int qb = rem >> 1, kvh = rem & 1;
  const int b = bh >> 4, h = bh & 15;
  const int qt = qb * 128 + w * 32;
  const int tb = kvh * 1024;

  const u16* Kbase = Ki + (size_t)b * 2048 * 1024 + h * 64;
  const u16* Vbase = Vt + (size_t)bh * 64 * 2048;

  // Q B-frags (col q = lq, k = s*16 + hi*8 + j), prescaled by log2(e)/8 (exp2 domain)
  bf16x8 qf[4];
  {
    const u16* qp = Qi + (size_t)(b * 2048 + qt + lq) * 1024 + h * 64 + hi * 8;
#pragma unroll
    for (int s = 0; s < 4; ++s) {
      u32x4 t4 = *(const u32x4*)(qp + s * 16);
      u16* tp = (u16*)&t4;
#pragma unroll
      for (int j = 0; j < 8; ++j) tp[j] = f2bf(bf2f(tp[j]) * 0.1803368867f);
      qf[s] = *(bf16x8*)&t4;
    }
  }

  f32x16 o0 = {}, o1 = {};
  float l_r = 0.f;

  // stage tile `t` into buffer `bb`: K [64 t-rows][64 k], V^T [64 d-rows][64 t]
  auto STAGE = [&](int bb, int t) {
#pragma unroll
    for (int i = 0; i < 2; ++i) {
      int r = i * 32 + w * 8 + lr;
      int sch = lch ^ (r & 7);
      gload_lds16(Kbase + (size_t)(tb + t * 64 + r) * 1024 + sch * 8,
                  Kl[bb] + i * 2048 + w * 512);
      gload_lds16(Vbase + (size_t)r * 2048 + tb + t * 64 + sch * 8,
                  Vl[bb] + i * 2048 + w * 512);
    }
  };

  STAGE(0, 0);

#pragma unroll 2
  for (int tile = 0; tile < 16; ++tile) {
    const int cur = tile & 1;
    __syncthreads();  // compiler drains vmcnt: staged tile `cur` ready
    if (tile + 1 < 16) STAGE(cur ^ 1, tile + 1);
    const u16* kl = Kl[cur];
    const u16* vl = Vl[cur];

    // S^T = K Q^T: two 32-t halves
    f32x16 s0 = {}, s1 = {};
    __builtin_amdgcn_s_setprio(1);
#pragma unroll
    for (int s = 0; s < 4; ++s) {
      int row = lq, c = s * 2 + hi;
      bf16x8 kf = *(const bf16x8*)(kl + row * 64 + (c ^ (row & 7)) * 8);
      s0 = __builtin_amdgcn_mfma_f32_32x32x16_bf16(kf, qf[s], s0, 0, 0, 0);
    }
#pragma unroll
    for (int s = 0; s < 4; ++s) {
      int row = 32 + lq, c = s * 2 + hi;
      bf16x8 kf = *(const bf16x8*)(kl + row * 64 + (c ^ (row & 7)) * 8);
      s1 = __builtin_amdgcn_mfma_f32_32x32x16_bf16(kf, qf[s], s1, 0, 0, 0);
    }
    __builtin_amdgcn_s_setprio(0);

    // P = exp2(S) via raw v_exp_f32; row-sum tree on VALU; pack; permlane half-swap
    float rs = 0.f;
    bf16x8 pa[4];
#pragma unroll
    for (int s4 = 0; s4 < 4; ++s4) {
      const int rb = 8 * (s4 & 1);
      float p[8];
#pragma unroll
      for (int j = 0; j < 8; ++j) {
        float sv = (s4 < 2) ? ((const float*)&s0)[rb + j] : ((const float*)&s1)[rb + j];
        p[j] = fexp2(sv);
      }
      rs += ((p[0] + p[1]) + (p[2] + p[3])) + ((p[4] + p[5]) + (p[6] + p[7]));
      u32 w10 = cvtpk(p[0], p[1]);
      u32 w11 = cvtpk(p[2], p[3]);
      u32 w20 = cvtpk(p[4], p[5]);
      u32 w21 = cvtpk(p[6], p[7]);
      plswap(w10, w20);  // w10 -> [w10.lo, w20.lo]; w20 -> [w10.hi, w20.hi]
      plswap(w11, w21);
      u32x4 af;
      af[0] = w10;
      af[1] = w11;
      af[2] = w20;
      af[3] = w21;
      pa[s4] = *(bf16x8*)&af;  // t-window s4*16
    }
    rs += __shfl_xor(rs, 32, 64);
    l_r += rs;

    // O += P V
    __builtin_amdgcn_s_setprio(1);
#pragma unroll
    for (int s4 = 0; s4 < 4; ++s4) {
      int rowd = lq, c = s4 * 2 + hi;
      bf16x8 vf = *(const bf16x8*)(vl + rowd * 64 + (c ^ (rowd & 7)) * 8);
      o0 = __builtin_amdgcn_mfma_f32_32x32x16_bf16(pa[s4], vf, o0, 0, 0, 0);
    }
#pragma unroll
    for (int s4 = 0; s4 < 4; ++s4) {
      int rowd = 32 + lq, c = s4 * 2 + hi;
      bf16x8 vf = *(const bf16x8*)(vl + rowd * 64 + (c ^ (rowd & 7)) * 8);
      o1 = __builtin_amdgcn_mfma_f32_32x32x16_bf16(pa[s4], vf, o1, 0, 0, 0);
    }
    __builtin_amdgcn_s_setprio(0);
  }

  // write unnormalized partials (D-layout: q(reg r) = (r&3)+8*(r>>2)+4*hi, d-col = lq)
#pragma unroll
  for (int r = 0; r < 16; ++r) {
    int qr = (r & 3) + 8 * (r >> 2) + 4 * hi;
    u16* hp = Op + (size_t)kvh * 4194304 + ((size_t)bh * 2048 + qt + qr) * 64;
    hp[lq] = f2bf(o0[r]);
    hp[32 + lq] = f2bf(o1[r]);
  }
  if (hi == 0) Lp[(size_t)kvh * 65536 + (size_t)bh * 2048 + qt + lq] = l_r;
}

// ---------------- combine: Hd = (Op0 + Op1) / (L0 + L1) ----------------
__global__ __launch_bounds__(256) void combine_kernel(const u16* __restrict__ Op,
                                                      const float* __restrict__ Lp,
                                                      u16* __restrict__ Hd) {
  const int idx = blockIdx.x * 256 + threadIdx.x;  // 524288 threads: row g, d-oct j
  const int g = idx >> 3, j = idx & 7;
  const float fac = 1.f / (Lp[g] + Lp[65536 + g]);
  const size_t off = (size_t)g * 64 + j * 8;
  u32x4 va = *(const u32x4*)(Op + off);
  u32x4 vb = *(const u32x4*)(Op + 4194304 + off);
  const u16* pa = (const u16*)&va;
  const u16* pb = (const u16*)&vb;
  u32x4 outv;
  u16* po = (u16*)&outv;
#pragma unroll
  for (int e = 0; e < 8; ++e) po[e] = f2bf((bf2f(pa[e]) + bf2f(pb[e])) * fac);
  *(u32x4*)(Hd + off) = outv;
}

// ---------------- launch ----------------
extern "C" void kernel_launch(void* const* d_in, const int* in_sizes, int n_in,
                              void* d_out, int out_size, void* d_ws, size_t ws_size,
                              hipStream_t stream) {
  const float* Q = (const float*)d_in[0];
  const float* K = (const float*)d_in[1];
  const float* V = (const float*)d_in[2];
  const float* WQ = (const float*)d_in[3];
  const float* WK = (const float*)d_in[4];
  const float* WV = (const float*)d_in[5];
  const float* WO = (const float*)d_in[6];
  float* out = (float*)d_out;

  size_t off = 0;
  char* ws = (char*)d_ws;
  auto nxt = [&](size_t n) { void* p = ws + off; off += (n + 255) & ~(size_t)255; return p; };
  u16* Qb = (u16*)nxt(3ull * 4096 * 1024 * 2);   // Qb,Kb,Vb contiguous (dead after proj GEMM)
  u16* Qi = (u16*)nxt(3ull * 4096 * 1024 * 2);   // Qi,Ki (z=2 writes Vtb instead)
  u16* Vtb = (u16*)nxt(4096ull * 1024 * 2);
  u16* Hd = (u16*)nxt(4096ull * 1024 * 2);
  u16* Wt = (u16*)nxt(3ull * 1048576 * 2);
  u16* Wot = (u16*)nxt(1048576ull * 2);
  float* Lp = (float*)nxt(2ull * 65536 * 4);
  u16* Ki = Qi + 4194304;
  // attention partials: Op[0..1] alias dead Qb region (16.8MB < 25.2MB)
  u16* Op = Qb;

  prep_tw_kernel<<<5120, 256, 0, stream>>>(Q, K, V, WQ, WK, WV, WO, Qb, Qb + 4194304,
                                           Qb + 2 * 4194304, Wt, Wot);

  // fused Q/K/V projections: z picks (A, W, C) triple; z==2 writes Vtb transposed
  gemm_proj_kernel<<<dim3(32, 8, 3), 256, 0, stream>>>(Qb, Wt, Qi, Vtb);

  attn_kernel<<<1024, 256, 0, stream>>>(Qi, Ki, Vtb, Op, Lp);

  combine_kernel<<<2048, 256, 0, stream>>>(Op, Lp, Hd);

  gemm_out_kernel<<<512, 256, 0, stream>>>(Hd, Wot, out);
}